// Round 1
// baseline (214.971 us; speedup 1.0000x reference)
//
#include <hip/hip_runtime.h>

// Problem constants (fixed by the harness / reference setup_inputs()).
constexpr int B = 16384;   // rows of x
constexpr int D = 2048;    // feature dim
constexpr float CLAMP_MIN = 1e-12f;
constexpr float CLAMP_MAX = 1e12f;

// One wave (64 lanes) per row; grid-stride over rows.
// Each lane reads 8 float4 (32 floats) of x and of the gathered center,
// accumulates sum((x-c)^2) locally, then a 64-lane butterfly produces the
// per-row squared distance, which is clipped and accumulated per wave.
__global__ __launch_bounds__(256) void center_loss_kernel(
    const float* __restrict__ x,
    const int* __restrict__ labels,
    const float* __restrict__ centers,
    float* __restrict__ out)
{
    const int lane           = threadIdx.x & 63;
    const int wave_in_block  = threadIdx.x >> 6;          // 0..3
    const int waves_per_block = blockDim.x >> 6;          // 4
    const int global_wave    = blockIdx.x * waves_per_block + wave_in_block;
    const int num_waves      = gridDim.x * waves_per_block;

    float acc = 0.0f;  // per-wave sum of clipped distances (valid on lane 0)

    for (int row = global_wave; row < B; row += num_waves) {
        const int lbl = labels[row];  // wave-uniform broadcast load
        const float4* __restrict__ xr =
            reinterpret_cast<const float4*>(x + (size_t)row * D);
        const float4* __restrict__ cr =
            reinterpret_cast<const float4*>(centers + (size_t)lbl * D);

        float partial = 0.0f;
        #pragma unroll
        for (int j = 0; j < D / 4 / 64; ++j) {  // 8 iterations
            float4 xv = xr[j * 64 + lane];
            float4 cv = cr[j * 64 + lane];
            float d0 = xv.x - cv.x;
            float d1 = xv.y - cv.y;
            float d2 = xv.z - cv.z;
            float d3 = xv.w - cv.w;
            partial = fmaf(d0, d0,
                      fmaf(d1, d1,
                      fmaf(d2, d2,
                      fmaf(d3, d3, partial))));
        }

        // 64-lane butterfly reduction (wave = 64 on CDNA).
        #pragma unroll
        for (int off = 32; off > 0; off >>= 1)
            partial += __shfl_xor(partial, off, 64);

        if (lane == 0) {
            float dist = fminf(fmaxf(partial, CLAMP_MIN), CLAMP_MAX);
            acc += dist;
        }
    }

    // Block-level reduction: one atomic per block.
    __shared__ float s[8];
    if (lane == 0) s[wave_in_block] = acc;
    __syncthreads();
    if (threadIdx.x == 0) {
        float bsum = 0.0f;
        for (int w = 0; w < waves_per_block; ++w) bsum += s[w];
        atomicAdd(out, bsum * (1.0f / (float)B));
    }
}

extern "C" void kernel_launch(void* const* d_in, const int* in_sizes, int n_in,
                              void* d_out, int out_size, void* d_ws, size_t ws_size,
                              hipStream_t stream) {
    const float* x       = (const float*)d_in[0];
    const int*   labels  = (const int*)d_in[1];
    const float* centers = (const float*)d_in[2];
    float*       out     = (float*)d_out;

    // d_out is poisoned (0xAA) before every timed replay — zero it first.
    hipMemsetAsync(out, 0, sizeof(float), stream);

    const int block = 256;                    // 4 waves/block
    const int grid  = 2048;                   // 8192 waves -> 2 rows each
    center_loss_kernel<<<grid, block, 0, stream>>>(x, labels, centers, out);
}

// Round 2
// 194.529 us; speedup vs baseline: 1.1051x; 1.1051x over previous
//
#include <hip/hip_runtime.h>

// Problem constants (fixed by the harness / reference setup_inputs()).
constexpr int B = 16384;   // rows of x
constexpr int D = 2048;    // feature dim
constexpr float CLAMP_MIN = 1e-12f;
constexpr float CLAMP_MAX = 1e12f;

constexpr int GRID1  = 2048;   // blocks in pass 1 (4 waves each -> 8192 waves, 2 rows/wave)
constexpr int BLOCK1 = 256;

// Pass 1: one wave (64 lanes) per row, grid-stride over rows.
// Each lane reads 8 float4 (32 floats) of x and of the gathered center,
// accumulates sum((x-c)^2), 64-lane butterfly -> per-row distance, clip,
// accumulate per wave; LDS-reduce the 4 wave sums; write ONE partial per
// block to d_ws (no atomics, no memset dependency).
__global__ __launch_bounds__(BLOCK1) void center_loss_pass1(
    const float* __restrict__ x,
    const int* __restrict__ labels,
    const float* __restrict__ centers,
    float* __restrict__ partials)
{
    const int lane            = threadIdx.x & 63;
    const int wave_in_block   = threadIdx.x >> 6;          // 0..3
    const int waves_per_block = BLOCK1 >> 6;               // 4
    const int global_wave     = blockIdx.x * waves_per_block + wave_in_block;
    const int num_waves       = GRID1 * waves_per_block;   // 8192

    float acc = 0.0f;  // per-wave sum of clipped distances (valid on lane 0)

    for (int row = global_wave; row < B; row += num_waves) {
        const int lbl = __builtin_amdgcn_readfirstlane(labels[row]);
        const float4* __restrict__ xr =
            reinterpret_cast<const float4*>(x + (size_t)row * D);
        const float4* __restrict__ cr =
            reinterpret_cast<const float4*>(centers + (size_t)lbl * D);

        float partial = 0.0f;
        #pragma unroll
        for (int j = 0; j < D / 4 / 64; ++j) {  // 8 iterations
            float4 xv = xr[j * 64 + lane];
            float4 cv = cr[j * 64 + lane];
            float d0 = xv.x - cv.x;
            float d1 = xv.y - cv.y;
            float d2 = xv.z - cv.z;
            float d3 = xv.w - cv.w;
            partial = fmaf(d0, d0,
                      fmaf(d1, d1,
                      fmaf(d2, d2,
                      fmaf(d3, d3, partial))));
        }

        // 64-lane butterfly reduction (wave = 64 on CDNA).
        #pragma unroll
        for (int off = 32; off > 0; off >>= 1)
            partial += __shfl_xor(partial, off, 64);

        if (lane == 0) {
            acc += fminf(fmaxf(partial, CLAMP_MIN), CLAMP_MAX);
        }
    }

    __shared__ float s[4];
    if (lane == 0) s[wave_in_block] = acc;
    __syncthreads();
    if (threadIdx.x == 0) {
        partials[blockIdx.x] = (s[0] + s[1]) + (s[2] + s[3]);
    }
}

// Pass 2: reduce GRID1 partials with a single block, scale by 1/B, write out.
__global__ __launch_bounds__(256) void center_loss_pass2(
    const float* __restrict__ partials,
    float* __restrict__ out)
{
    const int tid = threadIdx.x;
    float v = 0.0f;
    #pragma unroll
    for (int j = 0; j < GRID1 / 256; ++j)      // 8 values per thread
        v += partials[j * 256 + tid];

    // Wave butterfly
    #pragma unroll
    for (int off = 32; off > 0; off >>= 1)
        v += __shfl_xor(v, off, 64);

    __shared__ float s[4];
    if ((tid & 63) == 0) s[tid >> 6] = v;
    __syncthreads();
    if (tid == 0)
        out[0] = ((s[0] + s[1]) + (s[2] + s[3])) * (1.0f / (float)B);
}

extern "C" void kernel_launch(void* const* d_in, const int* in_sizes, int n_in,
                              void* d_out, int out_size, void* d_ws, size_t ws_size,
                              hipStream_t stream) {
    const float* x       = (const float*)d_in[0];
    const int*   labels  = (const int*)d_in[1];
    const float* centers = (const float*)d_in[2];
    float*       out     = (float*)d_out;
    float*       partials = (float*)d_ws;     // GRID1 floats of scratch

    center_loss_pass1<<<GRID1, BLOCK1, 0, stream>>>(x, labels, centers, partials);
    center_loss_pass2<<<1, 256, 0, stream>>>(partials, out);
}